// Round 7
// baseline (7338.472 us; speedup 1.0000x reference)
//
#include <hip/hip_runtime.h>
#include <hip/hip_bf16.h>
#include <hip/hip_fp16.h>
#include <cstdint>
#include <cstddef>

#define AS1 __attribute__((address_space(1)))
#define AS3 __attribute__((address_space(3)))

constexpr int HIDC   = 4096;
constexpr int INTERC = 11008;
constexpr int NTOKC  = 4096;          // B*S
constexpr int NWGU   = 2 * INTERC;    // 22016 gate_up weight cols

using f32x16 = __attribute__((ext_vector_type(16))) float;
using f16x8  = __attribute__((ext_vector_type(8))) _Float16;

// ---------------- prologue kernels ----------------

__global__ void cvt_x_kernel(const float4* __restrict__ x, ushort4* __restrict__ xh, int n4) {
  int stride = gridDim.x * blockDim.x;
  for (int i = blockIdx.x * blockDim.x + threadIdx.x; i < n4; i += stride) {
    float4 v = x[i];
    ushort4 o;
    o.x = __builtin_bit_cast(unsigned short, __float2half(v.x));
    o.y = __builtin_bit_cast(unsigned short, __float2half(v.y));
    o.z = __builtin_bit_cast(unsigned short, __float2half(v.z));
    o.w = __builtin_bit_cast(unsigned short, __float2half(v.w));
    xh[i] = o;
  }
}

// repack qweight [K][N/8] (nibbles along N) -> qt [K/32][N][4] (k-tile-major).
// Nibble order within each qword PERMUTED: k=j at pos (j&1)?4+(j>>1):(j>>1),
// so (q>>4i)&0x000F000F extracts the k-pair (2i,2i+1).
__global__ void repack_kernel(const uint32_t* __restrict__ qw, uint32_t* __restrict__ qt,
                              int K32, int Wn8) {
  long total  = (long)K32 * Wn8;
  long stride = (long)gridDim.x * blockDim.x;
  for (long idx = blockIdx.x * (long)blockDim.x + threadIdx.x; idx < total; idx += stride) {
    int kt2 = (int)(idx / Wn8);
    int cg  = (int)(idx - (long)kt2 * Wn8);
    uint32_t ow[8][4] = {};
#pragma unroll
    for (int kl = 0; kl < 32; ++kl) {
      uint32_t v = qw[(size_t)(kt2 * 32 + kl) * Wn8 + cg];
      const int kkl = kl >> 3, j = kl & 7;
      const int pos = (j & 1) ? (4 + (j >> 1)) : (j >> 1);
#pragma unroll
      for (int c = 0; c < 8; ++c)
        ow[c][kkl] |= ((v >> (4 * c)) & 0xFu) << (4 * pos);
    }
    uint4* dst = (uint4*)(qt + ((size_t)kt2 * Wn8 * 8 + (size_t)cg * 8) * 4);
#pragma unroll
    for (int c = 0; c < 8; ++c)
      dst[c] = make_uint4(ow[c][0], ow[c][1], ow[c][2], ow[c][3]);
  }
}

// tab[g][n] = ( half2(s,s), half2(-z*s,-z*s) ) packed as uint2
__global__ void mktab_kernel(const uint32_t* __restrict__ qz, const float* __restrict__ sc,
                             uint2* __restrict__ tab, int total, int Nw) {
  int stride = gridDim.x * blockDim.x;
  for (int idx = blockIdx.x * blockDim.x + threadIdx.x; idx < total; idx += stride) {
    int g = idx / Nw, n = idx - g * Nw;
    uint32_t z = (qz[(size_t)g * (Nw >> 3) + (n >> 3)] >> ((n & 7) * 4)) & 0xFu;
    float s = sc[idx];
    uint32_t us = (uint32_t)__builtin_bit_cast(unsigned short, __float2half(s));
    uint32_t uc = (uint32_t)__builtin_bit_cast(unsigned short, __float2half(-s * (float)z));
    tab[idx] = make_uint2(us | (us << 16), uc | (uc << 16));
  }
}

// -------- fused dequant GEMM, 128x256, single-buffer, 3 blocks/CU --------
// 512 threads = 8 waves (2M x 4N), wave-tile 64x64, 32x32x16 f16 MFMA.
// LDS 48KB single buffer: A[128][64] f16 @0 (16KB), B[256][64] f16 @16KB (32KB).
// XOR swizzle on 128B rows: byte ^= (row&7)<<4 (A: pre-swizzled global source
// for linear global_load_lds dest; B: write-side swizzle; reads swizzled same).
// Simple 2-barrier loop (R1-proven): cross-block overlap (3/CU) hides drains.
template <int DUAL, int NT, int NWTOT, int NNT, int K>
__global__ __launch_bounds__(512, 6) void qgemm_kernel(
    const __half* __restrict__ A, const uint32_t* __restrict__ QT,
    const uint2* __restrict__ TAB, __half* __restrict__ Hout,
    float* __restrict__ Fout) {
  __shared__ __align__(16) char lds[49152];

  const int tid  = threadIdx.x;
  const int lane = tid & 63;
  const int w    = tid >> 6;
  const int wr   = w >> 2, wc = w & 3;   // 2M x 4N waves
  const int fr   = lane & 31;            // 32x32 frag row/col
  const int khf  = lane >> 5;            // k-half within K=16 frag
  const int l7   = lane & 7;

  // bijective XCD chunking (grid%8==0); N varies fastest within a chunk so the
  // 4-Mtile A panel (4MB) stays in that XCD's L2 while weights stream via L3.
  const int nwg8 = (int)gridDim.x >> 3;
  const int g2   = (blockIdx.x & 7) * nwg8 + ((int)blockIdx.x >> 3);
  const int mt   = g2 / NNT;
  const int nt   = g2 - mt * NNT;
  const int row0 = mt * 128;

  // A staging: linear LDS dest, pre-swizzled global source.
  int a_src[2];
#pragma unroll
  for (int i = 0; i < 2; ++i) {
    int o = i * 8192 + tid * 16;
    int r = o >> 7;
    int b = (o & 127) ^ ((r & 7) << 4);
    a_src[i] = (row0 + r) * K + (b >> 1);
  }

  // B staging: thread owns LDS col tc, k-half khB (one uint4 = 32 nibbles).
  const int tc = tid & 255, khB = tid >> 8;
  int wcol;
  if (DUAL) {
    // 32-col gate/up interleave: LDS cols [p*64..p*64+31]=gate, [+32..63]=up of
    // h-cols nt*128 + p*32 + c32 -> each wave's 64 cols = one (gate,up) pair.
    const int bq = tc >> 5, matq = bq & 1, pq = bq >> 1, c32 = tc & 31;
    wcol = nt * 128 + pq * 32 + c32 + matq * INTERC;
  } else {
    wcol = nt * 256 + tc;
  }
  const int boff = 16384 + tc * 128;
  const int bswz = (tc & 7) << 4;

  auto qaddr = [&](int t) {
    return (const uint4*)(QT + ((size_t)(2 * t + khB) * NWTOT + wcol) * 4);
  };
  auto taddr = [&](int t) { return TAB + (size_t)(t >> 1) * NWTOT + wcol; };

  f32x16 acc[2][2] = {};   // [m 32-row block][n: DUAL gate/up, else 32-col block]

  uint4 qv = *qaddr(0);
  uint2 tv = *taddr(0);

#pragma unroll 1
  for (int kt = 0; kt < NT; ++kt) {
    if (kt) __syncthreads();   // previous compute's LDS reads done

    // --- A stage: 2x global_load_lds width 16 ---
#pragma unroll
    for (int i = 0; i < 2; ++i)
      __builtin_amdgcn_global_load_lds((const AS1 uint32_t*)(A + a_src[i] + kt * 64),
                                       (AS3 uint32_t*)(lds + i * 8192 + w * 1024),
                                       16, 0, 0);

    // --- B dequant: 4 packed words -> 4x ds_write_b128 (swizzled) ---
    {
      const __half2 s2 = __builtin_bit_cast(__half2, tv.x);
      const __half2 c2 = __builtin_bit_cast(__half2, tv.y);
      const __half2 k1024 = __builtin_bit_cast(__half2, 0x64006400u);
      uint32_t qq[4] = {qv.x, qv.y, qv.z, qv.w};
#pragma unroll
      for (int p = 0; p < 4; ++p) {
        uint32_t r_[4];
#pragma unroll
        for (int i = 0; i < 4; ++i) {
          uint32_t pr = ((qq[p] >> (4 * i)) & 0x000F000Fu) | 0x64006400u;
          __half2 t  = __hsub2(__builtin_bit_cast(__half2, pr), k1024);  // exact pair
          __half2 wv = __hfma2(t, s2, c2);                               // n*s - z*s
          r_[i] = __builtin_bit_cast(uint32_t, wv);
        }
        *(uint4*)(lds + boff + ((khB * 64 + p * 16) ^ bswz)) =
            make_uint4(r_[0], r_[1], r_[2], r_[3]);
      }
    }
    __syncthreads();           // drains vmcnt(0)+lgkmcnt(0): tile fully staged

    if (kt + 1 < NT) {         // prefetch next q/tab AFTER the drain barrier:
      qv = *qaddr(kt + 1);     // latency hides under compute below
      tv = *taddr(kt + 1);
    }

    // --- compute: 4 k-slices x (2m x 2n) 32x32x16 MFMA ---
#pragma unroll
    for (int s = 0; s < 4; ++s) {
      const int bb = ((s * 2 + khf) ^ l7) << 4;
      f16x8 av[2], bv[2];
#pragma unroll
      for (int m = 0; m < 2; ++m)
        av[m] = *(const f16x8*)(lds + (wr * 64 + m * 32 + fr) * 128 + bb);
#pragma unroll
      for (int n = 0; n < 2; ++n)
        bv[n] = *(const f16x8*)(lds + 16384 + (wc * 64 + n * 32 + fr) * 128 + bb);
#pragma unroll
      for (int m = 0; m < 2; ++m)
#pragma unroll
        for (int n = 0; n < 2; ++n)
          acc[m][n] = __builtin_amdgcn_mfma_f32_32x32x16_f16(av[m], bv[n], acc[m][n], 0, 0, 0);
    }
  }

  // ---- epilogue — 32x32 C/D map: col = lane&31, row = (reg&3)+8*(reg>>2)+4*(lane>>5) ----
  if (DUAL) {
    const int hcol = nt * 128 + wc * 32 + fr;
#pragma unroll
    for (int m = 0; m < 2; ++m) {
      const int rbase = row0 + wr * 64 + m * 32 + khf * 4;
#pragma unroll
      for (int r = 0; r < 16; ++r) {
        const int row = rbase + (r & 3) + ((r >> 2) << 3);
        float gv = acc[m][0][r];
        float uv = acc[m][1][r];
        float hv = gv / (1.0f + __expf(-gv)) * uv;   // silu(g)*u
        Hout[(size_t)row * INTERC + hcol] = __float2half(hv);
      }
    }
  } else {
#pragma unroll
    for (int m = 0; m < 2; ++m) {
      const int rbase = row0 + wr * 64 + m * 32 + khf * 4;
#pragma unroll
      for (int n = 0; n < 2; ++n) {
        const int cc = nt * 256 + wc * 64 + n * 32 + fr;
#pragma unroll
        for (int r = 0; r < 16; ++r) {
          const int row = rbase + (r & 3) + ((r >> 2) << 3);
          Fout[(size_t)row * HIDC + cc] = acc[m][n][r];
        }
      }
    }
  }
}

// ---------------- launch ----------------
extern "C" void kernel_launch(void* const* d_in, const int* in_sizes, int n_in,
                              void* d_out, int out_size, void* d_ws, size_t ws_size,
                              hipStream_t stream) {
  const float*    x     = (const float*)d_in[0];
  const uint32_t* qw_gu = (const uint32_t*)d_in[1];
  const uint32_t* qz_gu = (const uint32_t*)d_in[2];
  const float*    sc_gu = (const float*)d_in[3];
  const uint32_t* qw_dn = (const uint32_t*)d_in[4];
  const uint32_t* qz_dn = (const uint32_t*)d_in[5];
  const float*    sc_dn = (const float*)d_in[6];
  float* out = (float*)d_out;

  // workspace layout (bytes), ~199.8 MB
  char* ws = (char*)d_ws;
  __half*   xh   = (__half*)(ws + 0);                 // 33,554,432
  uint32_t* qtgu = (uint32_t*)(ws + 33554432);        // 45,088,768
  uint32_t* qtdn = (uint32_t*)(ws + 78643200);        // 22,544,384
  uint2*    tgu  = (uint2*)(ws + 101187584);          //  5,636,096
  uint2*    tdn  = (uint2*)(ws + 106823680);          //  2,818,048
  __half*   hbuf = (__half*)(ws + 109641728);         // 90,177,536

  cvt_x_kernel<<<2048, 256, 0, stream>>>((const float4*)x, (ushort4*)xh, NTOKC * HIDC / 4);
  repack_kernel<<<2048, 256, 0, stream>>>(qw_gu, qtgu, HIDC / 32, NWGU / 8);
  repack_kernel<<<2048, 256, 0, stream>>>(qw_dn, qtdn, INTERC / 32, HIDC / 8);
  mktab_kernel<<<1024, 256, 0, stream>>>(qz_gu, sc_gu, tgu, (HIDC / 128) * NWGU, NWGU);
  mktab_kernel<<<1024, 256, 0, stream>>>(qz_dn, sc_dn, tdn, (INTERC / 128) * HIDC, HIDC);

  // GEMM1: x[4096x4096] @ W_gu -> silu*mul -> h f16 [4096x11008]; 86N x 32M = 2752 blocks
  qgemm_kernel<1, 64, NWGU, 86, HIDC>
      <<<2752, 512, 0, stream>>>(xh, qtgu, tgu, hbuf, nullptr);
  // GEMM2: h @ W_dn -> out f32 [4096x4096]; 16N x 32M = 512 blocks
  qgemm_kernel<0, 172, HIDC, 16, INTERC>
      <<<512, 512, 0, stream>>>(hbuf, qtdn, tdn, nullptr, out);
}

// Round 9
// 1300.323 us; speedup vs baseline: 5.6436x; 5.6436x over previous
//
#include <hip/hip_runtime.h>
#include <hip/hip_bf16.h>
#include <hip/hip_fp16.h>
#include <cstdint>
#include <cstddef>

#define AS1 __attribute__((address_space(1)))
#define AS3 __attribute__((address_space(3)))

constexpr int HIDC   = 4096;
constexpr int INTERC = 11008;
constexpr int NTOKC  = 4096;          // B*S
constexpr int NWGU   = 2 * INTERC;    // 22016 gate_up weight cols

using f32x4 = __attribute__((ext_vector_type(4))) float;
using f16x8 = __attribute__((ext_vector_type(8))) _Float16;

// ---------------- prologue kernels (K2-proven versions) ----------------

// x f32 -> f16
__global__ void cvt_x_kernel(const float4* __restrict__ x, ushort4* __restrict__ xh, int n4) {
  int stride = gridDim.x * blockDim.x;
  for (int i = blockIdx.x * blockDim.x + threadIdx.x; i < n4; i += stride) {
    float4 v = x[i];
    ushort4 o;
    o.x = __builtin_bit_cast(unsigned short, __float2half(v.x));
    o.y = __builtin_bit_cast(unsigned short, __float2half(v.y));
    o.z = __builtin_bit_cast(unsigned short, __float2half(v.z));
    o.w = __builtin_bit_cast(unsigned short, __float2half(v.w));
    xh[i] = o;
  }
}

// repack qweight [K][N/8] (nibbles along N) -> qt [N][K/8] nibbles along K in
// PERMUTED order: k=j lands at nibble pos (j&1) ? 4+(j>>1) : (j>>1), so that
// (q >> 4i) & 0x000F000F extracts the k-pair (2i, 2i+1).   [K2 verbatim]
__global__ void repack_kernel(const uint32_t* __restrict__ qw, uint32_t* __restrict__ qt,
                              int kints, int Wn) {
  long total  = (long)Wn * kints;
  long stride = (long)gridDim.x * blockDim.x;
  for (long idx = blockIdx.x * (long)blockDim.x + threadIdx.x; idx < total; idx += stride) {
    int col = (int)(idx / kints);
    int kk  = (int)(idx - (long)col * kints);
    uint32_t ow[8] = {0, 0, 0, 0, 0, 0, 0, 0};
#pragma unroll
    for (int j = 0; j < 8; ++j) {
      uint32_t v = qw[(size_t)(kk * 8 + j) * Wn + col];
      const int pos = (j & 1) ? (4 + (j >> 1)) : (j >> 1);
#pragma unroll
      for (int jn = 0; jn < 8; ++jn)
        ow[jn] |= ((v >> (4 * jn)) & 0xFu) << (4 * pos);
    }
#pragma unroll
    for (int jn = 0; jn < 8; ++jn)
      qt[(size_t)(col * 8 + jn) * kints + kk] = ow[jn];
  }
}

// tab[g][n] = ( half2(s,s), half2(-z*s,-z*s) ) packed as uint2   [K2 verbatim]
__global__ void mktab_kernel(const uint32_t* __restrict__ qz, const float* __restrict__ sc,
                             uint2* __restrict__ tab, int total, int Nw) {
  int stride = gridDim.x * blockDim.x;
  for (int idx = blockIdx.x * blockDim.x + threadIdx.x; idx < total; idx += stride) {
    int g = idx / Nw, n = idx - g * Nw;
    uint32_t z = (qz[(size_t)g * (Nw >> 3) + (n >> 3)] >> ((n & 7) * 4)) & 0xFu;
    float s = sc[idx];
    uint32_t us = (uint32_t)__builtin_bit_cast(unsigned short, __float2half(s));
    uint32_t uc = (uint32_t)__builtin_bit_cast(unsigned short, __float2half(-s * (float)z));
    tab[idx] = make_uint2(us | (us << 16), uc | (uc << 16));
  }
}

// ---------------- fused dequant GEMM (R1 structure, f16 dequant) ----------------
// DUAL=1: gate_up GEMM (dual accumulators, SiLU*mul epilogue, f16 h out), N-tile=64
// DUAL=0: down GEMM (f32 out), N-tile=128
// BM=128, BK=64, 256 threads (4 waves, 2x2). 2D grid: blockIdx.x=nt, blockIdx.y=mt.
// LDS: A tile [128][64] f16 @0 (16KB), B tile(s) [rows][64] f16 @16KB (16KB).
// XOR swizzle on the 128B rows: byte ^= (row&7)<<4  (both A and B, write+read sides).
template <int DUAL, int KSTEPS, int KINTS, int NWTOT>
__global__ __launch_bounds__(256, 2) void qgemm_kernel(
    const __half* __restrict__ A, const uint32_t* __restrict__ QT,
    const uint2* __restrict__ TAB, __half* __restrict__ Hout,
    float* __restrict__ Fout) {
  constexpr int K  = KSTEPS * 64;
  constexpr int NI = DUAL ? 2 : 4;
  __shared__ __align__(16) char lds[32768];

  const int tid  = threadIdx.x;
  const int lane = tid & 63;
  const int w    = tid >> 6;
  const int wr   = w >> 1, wc = w & 1;
  const int fr   = lane & 15;
  const int fq   = lane >> 4;
  const int nt   = blockIdx.x, mt = blockIdx.y;
  const int row0 = mt * 128;

  // A staging: linear LDS slot o holds logical element (r, b^((r&7)<<4)).
  // global_load_lds dest = wave-uniform base + lane*16, so pre-swizzle the SOURCE.
  int a_src[4];
#pragma unroll
  for (int i = 0; i < 4; ++i) {
    int o = i * 4096 + tid * 16;
    int r = o >> 7;
    int b = (o & 127) ^ ((r & 7) << 4);
    a_src[i] = (row0 + r) * K + (b >> 1);
  }

  // B staging coords (R1 verbatim): thread owns one weight row (n) and half its BK span.
  int s_mat, s_nl, s_kh, s_nglob;
  if (DUAL) {
    s_mat = tid >> 7;            // 0=gate, 1=up
    int tt = tid & 127;
    s_nl  = tt >> 1;             // 0..63
    s_kh  = tt & 1;
    s_nglob = nt * 64 + s_nl + (s_mat ? INTERC : 0);
  } else {
    s_mat = 0;
    s_nl  = tid >> 1;            // 0..127
    s_kh  = tid & 1;
    s_nglob = nt * 128 + s_nl;
  }
  char* bdst = lds + 16384 + s_mat * 8192 + s_nl * 128;
  const int bswz = (s_nl & 7) << 4;

  f32x4 acc0[4][NI] = {};
  f32x4 acc1[4][NI] = {};   // DCE'd when !DUAL

#pragma unroll 1
  for (int kt = 0; kt < KSTEPS; ++kt) {
    if (kt) __syncthreads();   // protect LDS from previous compute readers

    // --- A stage: 4x global_load_lds width 16 ---
#pragma unroll
    for (int i = 0; i < 4; ++i) {
      const __half* src = A + a_src[i] + kt * 64;
      __builtin_amdgcn_global_load_lds((const AS1 uint32_t*)src,
                                       (AS3 uint32_t*)(lds + i * 4096 + w * 1024),
                                       16, 0, 0);
    }

    // --- B stage: load 4 packed int32 (32 nibbles along K), f16 dequant, write ---
    {
      const uint32_t* qp = QT + (size_t)s_nglob * KINTS + kt * 8 + s_kh * 4;
      uint4 q = *(const uint4*)qp;
      uint2 tz = TAB[(size_t)(kt >> 1) * NWTOT + s_nglob];
      const __half2 s2 = __builtin_bit_cast(__half2, tz.x);
      const __half2 c2 = __builtin_bit_cast(__half2, tz.y);
      const __half2 k1024 = __builtin_bit_cast(__half2, 0x64006400u);
      uint32_t qq[4] = {q.x, q.y, q.z, q.w};
#pragma unroll
      for (int p = 0; p < 4; ++p) {
        uint32_t r_[4];
#pragma unroll
        for (int i = 0; i < 4; ++i) {
          uint32_t pr = ((qq[p] >> (4 * i)) & 0x000F000Fu) | 0x64006400u;
          __half2 t  = __hsub2(__builtin_bit_cast(__half2, pr), k1024);  // exact pair
          __half2 wv = __hfma2(t, s2, c2);                               // n*s - z*s
          r_[i] = __builtin_bit_cast(uint32_t, wv);
        }
        *(uint4*)(bdst + ((s_kh * 64 + p * 16) ^ bswz)) =
            make_uint4(r_[0], r_[1], r_[2], r_[3]);
      }
    }
    __syncthreads();   // compiler drains vmcnt(0)+lgkmcnt(0) before s_barrier

    // --- compute: 2 x K=32 MFMA sub-steps (R1 verbatim) ---
#pragma unroll
    for (int kk = 0; kk < 2; ++kk) {
      const int bb = (((kk << 2) | fq) ^ (fr & 7)) << 4;  // swizzled k-byte
      f16x8 av[4];
#pragma unroll
      for (int mi = 0; mi < 4; ++mi)
        av[mi] = *(const f16x8*)(lds + (wr * 64 + mi * 16 + fr) * 128 + bb);
      if (DUAL) {
#pragma unroll
        for (int ni = 0; ni < 2; ++ni) {
          const int brow = (wc * 32 + ni * 16 + fr) * 128 + bb;
          f16x8 bg = *(const f16x8*)(lds + 16384 + brow);
          f16x8 bu = *(const f16x8*)(lds + 24576 + brow);
#pragma unroll
          for (int mi = 0; mi < 4; ++mi) {
            acc0[mi][ni] = __builtin_amdgcn_mfma_f32_16x16x32_f16(av[mi], bg, acc0[mi][ni], 0, 0, 0);
            acc1[mi][ni] = __builtin_amdgcn_mfma_f32_16x16x32_f16(av[mi], bu, acc1[mi][ni], 0, 0, 0);
          }
        }
      } else {
#pragma unroll
        for (int ni = 0; ni < 4; ++ni) {
          f16x8 bv = *(const f16x8*)(lds + 16384 + (wc * 64 + ni * 16 + fr) * 128 + bb);
#pragma unroll
          for (int mi = 0; mi < 4; ++mi)
            acc0[mi][ni] = __builtin_amdgcn_mfma_f32_16x16x32_f16(av[mi], bv, acc0[mi][ni], 0, 0, 0);
        }
      }
    }
  }

  // --- epilogue ---  C/D map: col = lane&15, row = (lane>>4)*4 + reg  [m89-verified]
  if (DUAL) {
    const int col0 = nt * 64 + wc * 32;
#pragma unroll
    for (int mi = 0; mi < 4; ++mi) {
      const int rr = row0 + wr * 64 + mi * 16 + fq * 4;
#pragma unroll
      for (int ni = 0; ni < NI; ++ni) {
        const int cc = col0 + ni * 16 + fr;
#pragma unroll
        for (int r = 0; r < 4; ++r) {
          float gv = acc0[mi][ni][r];
          float uv = acc1[mi][ni][r];
          float hv = gv / (1.0f + __expf(-gv)) * uv;   // silu(g)*u
          Hout[(size_t)(rr + r) * INTERC + cc] = __float2half(hv);
        }
      }
    }
  } else {
    const int col0 = nt * 128 + wc * 64;
#pragma unroll
    for (int mi = 0; mi < 4; ++mi) {
      const int rr = row0 + wr * 64 + mi * 16 + fq * 4;
#pragma unroll
      for (int ni = 0; ni < NI; ++ni) {
        const int cc = col0 + ni * 16 + fr;
#pragma unroll
        for (int r = 0; r < 4; ++r)
          Fout[(size_t)(rr + r) * HIDC + cc] = acc0[mi][ni][r];
      }
    }
  }
}

// ---------------- launch ----------------
extern "C" void kernel_launch(void* const* d_in, const int* in_sizes, int n_in,
                              void* d_out, int out_size, void* d_ws, size_t ws_size,
                              hipStream_t stream) {
  const float*    x     = (const float*)d_in[0];
  const uint32_t* qw_gu = (const uint32_t*)d_in[1];
  const uint32_t* qz_gu = (const uint32_t*)d_in[2];
  const float*    sc_gu = (const float*)d_in[3];
  const uint32_t* qw_dn = (const uint32_t*)d_in[4];
  const uint32_t* qz_dn = (const uint32_t*)d_in[5];
  const float*    sc_dn = (const float*)d_in[6];
  float* out = (float*)d_out;

  // workspace layout (bytes), ~199.8 MB
  char* ws = (char*)d_ws;
  __half*   xh   = (__half*)(ws + 0);                 // 33,554,432
  uint32_t* qtgu = (uint32_t*)(ws + 33554432);        // 45,088,768
  uint32_t* qtdn = (uint32_t*)(ws + 78643200);        // 22,544,384
  uint2*    tgu  = (uint2*)(ws + 101187584);          //  5,636,096
  uint2*    tdn  = (uint2*)(ws + 106823680);          //  2,818,048
  __half*   hbuf = (__half*)(ws + 109641728);         // 90,177,536

  cvt_x_kernel<<<2048, 256, 0, stream>>>((const float4*)x, (ushort4*)xh, NTOKC * HIDC / 4);
  repack_kernel<<<2048, 256, 0, stream>>>(qw_gu, qtgu, HIDC / 8, NWGU / 8);
  repack_kernel<<<2048, 256, 0, stream>>>(qw_dn, qtdn, INTERC / 8, HIDC / 8);
  mktab_kernel<<<1024, 256, 0, stream>>>(qz_gu, sc_gu, tgu, (HIDC / 128) * NWGU, NWGU);
  mktab_kernel<<<1024, 256, 0, stream>>>(qz_dn, sc_dn, tdn, (INTERC / 128) * HIDC, HIDC);

  // GEMM1: [4096 x 4096] @ dequant(W_gu) -> silu*mul -> h f16 [4096 x 11008]
  qgemm_kernel<1, 64, 512, NWGU>
      <<<dim3(INTERC / 64, NTOKC / 128), 256, 0, stream>>>(xh, qtgu, tgu, hbuf, nullptr);
  // GEMM2: h @ dequant(W_dn) -> out f32 [4096 x 4096]
  qgemm_kernel<0, 172, 1376, HIDC>
      <<<dim3(HIDC / 128, NTOKC / 128), 256, 0, stream>>>(hbuf, qtdn, tdn, nullptr, out);
}

// Round 10
// 1100.516 us; speedup vs baseline: 6.6682x; 1.1816x over previous
//
#include <hip/hip_runtime.h>
#include <hip/hip_bf16.h>
#include <hip/hip_fp16.h>
#include <cstdint>
#include <cstddef>

#define AS1 __attribute__((address_space(1)))
#define AS3 __attribute__((address_space(3)))

constexpr int HIDC   = 4096;
constexpr int INTERC = 11008;
constexpr int NTOKC  = 4096;          // B*S

using f32x4 = __attribute__((ext_vector_type(4))) float;
using f16x8 = __attribute__((ext_vector_type(8))) _Float16;

// ---------------- prologue kernels ----------------

// x f32 -> f16
__global__ void cvt_x_kernel(const float4* __restrict__ x, ushort4* __restrict__ xh, int n4) {
  int stride = gridDim.x * blockDim.x;
  for (int i = blockIdx.x * blockDim.x + threadIdx.x; i < n4; i += stride) {
    float4 v = x[i];
    ushort4 o;
    o.x = __builtin_bit_cast(unsigned short, __float2half(v.x));
    o.y = __builtin_bit_cast(unsigned short, __float2half(v.y));
    o.z = __builtin_bit_cast(unsigned short, __float2half(v.z));
    o.w = __builtin_bit_cast(unsigned short, __float2half(v.w));
    xh[i] = o;
  }
}

// Dequantize a column-chunk of W into WT[n'][K] f16 (row-major over output cols).
// GU=1: n' is the gate/up 16-col interleave of orig col n = mat*INTERC + hc:
//       n' = (hc>>4)*32 + mat*16 + (hc&15)  (inverse: hc=(n'>>5)*16+(n'&15), mat=(n'>>4)&1)
// GU=0: n' = n.
// Block = 64 n' x 32 k tile; 256 threads = 32 k x 8 word-slots.
template <int GU>
__global__ void deq_kernel(const uint32_t* __restrict__ qw, const uint32_t* __restrict__ qz,
                           const float* __restrict__ sc, __half* __restrict__ WT,
                           int cbase, int K, int Wn8, int Nsc) {
  __shared__ __align__(16) __half tile[64][32];
  const int tid = threadIdx.x;
  const int bx = blockIdx.x;
  const int k0 = blockIdx.y * 32;
  const int k  = tid & 31, ws = tid >> 5;
  const int g  = (k0 + k) >> 7;        // k0 is 32-aligned; group const per block row
  int wordidx, nbase, nploc0;
  if (GU) {
    const int n0p = cbase + bx * 64;   // n' base (64-aligned)
    const int h0  = n0p >> 1;          // hc base (32 hc values per 64 n')
    const int mat = ws >> 2, wsq = ws & 3;
    wordidx = (mat * INTERC + h0) / 8 + wsq;
    nbase   = mat * INTERC + h0 + wsq * 8;
    nploc0  = ((wsq >> 1) << 5) + mat * 16 + ((wsq & 1) << 3);
  } else {
    const int n0 = cbase + bx * 64;
    wordidx = n0 / 8 + ws;
    nbase   = n0 + ws * 8;
    nploc0  = ws * 8;
  }
  uint32_t q  = qw[(size_t)(k0 + k) * Wn8 + wordidx];
  uint32_t zw = qz[(size_t)g * Wn8 + wordidx];
#pragma unroll
  for (int j = 0; j < 8; ++j) {
    float v = (float)((q >> (4 * j)) & 0xFu);
    float z = (float)((zw >> (4 * j)) & 0xFu);
    float s = sc[(size_t)g * Nsc + nbase + j];
    tile[nploc0 + j][k] = __float2half((v - z) * s);
  }
  __syncthreads();
  const int nl = tid >> 2, kc = (tid & 3) * 8;
  uint4 vv = *(const uint4*)&tile[nl][kc];
  *(uint4*)&WT[(size_t)(bx * 64 + nl) * K + k0 + kc] = vv;
}

// -------- pure-f16 GEMM, 256x256, counted-vmcnt depth-1.5 pipeline --------
// 512 threads = 8 waves (2M x 4N), per-wave 128x64 out, BK=64, 16x16x32 f16 MFMA.
// LDS 128KB: 2 bufs x (A[256][64] 32KB + B[256][64] 32KB), XOR swizzle
// byte ^= (row&7)<<4 via pre-swizzled gload SOURCE (LDS dest linear).
// Per tile: 4 phases (mh0kk0, mh0kk1, mh1kk0, mh1kk1); stage next tile as
// B0,B1 | B2,B3 | A0,A2 (rows 0-63,128-191) | A1,A3 (rows 64-127,192-255).
// Waits: end-ph2 vmcnt(4) (retires THIS tile's A-h1), end-ph4 vmcnt(2)
// (retires next tile's B + A-h0; A-h1 stays in flight). Never vmcnt(0) mid-loop.
template <int DUAL, int NT, int K>
__global__ __launch_bounds__(512, 1) void qgemm_kernel(
    const __half* __restrict__ A, const __half* __restrict__ B,
    __half* __restrict__ Hout, float* __restrict__ Fout) {
  __shared__ __align__(16) char lds[131072];
  const int tid  = threadIdx.x;
  const int lane = tid & 63;
  const int w    = tid >> 6;
  const int wr   = w >> 2, wc = w & 3;
  const int fr   = lane & 15, fq = lane >> 4;
  const int nt   = blockIdx.x, mt = blockIdx.y;
  const int row0 = mt * 256, col0 = nt * 256;

  int a_src[4], b_src[4];
#pragma unroll
  for (int i = 0; i < 4; ++i) {
    int o = i * 8192 + tid * 16;
    int r = o >> 7;
    int b = (o & 127) ^ ((r & 7) << 4);
    a_src[i] = (row0 + r) * K + (b >> 1);
    b_src[i] = (col0 + r) * K + (b >> 1);
  }

  f32x4 acc[8][4] = {};
  f16x8 av[4], bv0[4], bv1[4];

  auto glA = [&](int i, int kt, int buf) {
    __builtin_amdgcn_global_load_lds(
        (const AS1 uint32_t*)(A + (size_t)a_src[i] + (size_t)kt * 64),
        (AS3 uint32_t*)(lds + buf * 65536 + i * 8192 + w * 1024), 16, 0, 0);
  };
  auto glB = [&](int i, int kt, int buf) {
    __builtin_amdgcn_global_load_lds(
        (const AS1 uint32_t*)(B + (size_t)b_src[i] + (size_t)kt * 64),
        (AS3 uint32_t*)(lds + buf * 65536 + 32768 + i * 8192 + w * 1024), 16, 0, 0);
  };
  auto rdA = [&](int buf, int mh, int kk) {
    const int bb = (((kk << 2) | fq) ^ (fr & 7)) << 4;
    const char* base = lds + buf * 65536;
#pragma unroll
    for (int j = 0; j < 4; ++j)
      av[j] = *(const f16x8*)(base + (wr * 128 + mh * 64 + j * 16 + fr) * 128 + bb);
  };
  auto rdB = [&](int buf, int kk, f16x8* dst) {
    const int bb = (((kk << 2) | fq) ^ (fr & 7)) << 4;
    const char* base = lds + buf * 65536 + 32768;
#pragma unroll
    for (int n = 0; n < 4; ++n)
      dst[n] = *(const f16x8*)(base + (wc * 64 + n * 16 + fr) * 128 + bb);
  };
  auto mfma16 = [&](f16x8* bvp, int mh) {
    __builtin_amdgcn_s_setprio(1);
#pragma unroll
    for (int j = 0; j < 4; ++j)
#pragma unroll
      for (int n = 0; n < 4; ++n)
        acc[mh * 4 + j][n] =
            __builtin_amdgcn_mfma_f32_16x16x32_f16(av[j], bvp[n], acc[mh * 4 + j][n], 0, 0, 0);
    __builtin_amdgcn_s_setprio(0);
  };

  // prologue: tile 0, issue order B0..B3, A0, A2, A1, A3; leave A-h1 in flight
  glB(0, 0, 0); glB(1, 0, 0); glB(2, 0, 0); glB(3, 0, 0);
  glA(0, 0, 0); glA(2, 0, 0); glA(1, 0, 0); glA(3, 0, 0);
  asm volatile("s_waitcnt vmcnt(2)" ::: "memory");
  asm volatile("s_barrier" ::: "memory");

#pragma unroll 1
  for (int kt = 0; kt < NT; ++kt) {
    const int cur = kt & 1, nxt = cur ^ 1;
    const bool stg = (kt + 1 < NT);
    // ph1: (mh0, kk0)
    if (stg) { glB(0, kt + 1, nxt); glB(1, kt + 1, nxt); }
    rdB(cur, 0, bv0);
    rdA(cur, 0, 0);
    mfma16(bv0, 0);
    // ph2: (mh0, kk1)
    if (stg) { glB(2, kt + 1, nxt); glB(3, kt + 1, nxt); }
    rdB(cur, 1, bv1);
    rdA(cur, 0, 1);
    mfma16(bv1, 0);
    if (stg) asm volatile("s_waitcnt vmcnt(4)" ::: "memory");
    else     asm volatile("s_waitcnt vmcnt(0)" ::: "memory");
    asm volatile("s_barrier" ::: "memory");
    // ph3: (mh1, kk0)
    if (stg) { glA(0, kt + 1, nxt); glA(2, kt + 1, nxt); }
    rdA(cur, 1, 0);
    mfma16(bv0, 1);
    // ph4: (mh1, kk1)
    if (stg) { glA(1, kt + 1, nxt); glA(3, kt + 1, nxt); }
    rdA(cur, 1, 1);
    mfma16(bv1, 1);
    if (stg) asm volatile("s_waitcnt vmcnt(2)" ::: "memory");
    asm volatile("s_barrier" ::: "memory");
  }

  // ---- epilogue — C/D map: col = lane&15, row = (lane>>4)*4 + reg ----
  if (DUAL) {
#pragma unroll
    for (int mi = 0; mi < 8; ++mi) {
      const int rr = row0 + wr * 128 + mi * 16 + fq * 4;
#pragma unroll
      for (int pp = 0; pp < 2; ++pp) {
        const int hcol = nt * 128 + (wc * 2 + pp) * 16 + fr;
#pragma unroll
        for (int r = 0; r < 4; ++r) {
          float gv = acc[mi][2 * pp][r];
          float uv = acc[mi][2 * pp + 1][r];
          float hv = gv / (1.0f + __expf(-gv)) * uv;   // silu(g)*u
          Hout[(size_t)(rr + r) * INTERC + hcol] = __float2half(hv);
        }
      }
    }
  } else {
#pragma unroll
    for (int mi = 0; mi < 8; ++mi) {
      const int rr = row0 + wr * 128 + mi * 16 + fq * 4;
#pragma unroll
      for (int ni = 0; ni < 4; ++ni) {
        const int cc = nt * 256 + wc * 64 + ni * 16 + fr;
#pragma unroll
        for (int r = 0; r < 4; ++r)
          Fout[(size_t)(rr + r) * HIDC + cc] = acc[mi][ni][r];
      }
    }
  }
}

// ---------------- launch ----------------
extern "C" void kernel_launch(void* const* d_in, const int* in_sizes, int n_in,
                              void* d_out, int out_size, void* d_ws, size_t ws_size,
                              hipStream_t stream) {
  const float*    x     = (const float*)d_in[0];
  const uint32_t* qw_gu = (const uint32_t*)d_in[1];
  const uint32_t* qz_gu = (const uint32_t*)d_in[2];
  const float*    sc_gu = (const float*)d_in[3];
  const uint32_t* qw_dn = (const uint32_t*)d_in[4];
  const uint32_t* qz_dn = (const uint32_t*)d_in[5];
  const float*    sc_dn = (const float*)d_in[6];
  float* out = (float*)d_out;

  // workspace (186.6 MB peak):
  //   [0, 33.5MB)      xh (f16 x)          — dead after GEMM1
  //   [33.5, 96.5MB)   WT gu chunk (<=62.9MB)
  //   [96.5, 186.6MB)  hbuf (f16 h)
  //   WTdn (90.2MB) reuses [0, 90.2MB) after GEMM1 completes (stream-ordered)
  char* ws = (char*)d_ws;
  __half* xh   = (__half*)(ws);
  __half* WT   = (__half*)(ws + 33554432);
  __half* hbuf = (__half*)(ws + 96468992);
  __half* WTdn = (__half*)(ws);

  cvt_x_kernel<<<2048, 256, 0, stream>>>((const float4*)x, (ushort4*)xh, NTOKC * HIDC / 4);

  // GEMM1 in 3 col' chunks (7680, 7680, 6656 of 22016): deq -> GEMM -> next
  const int cb[3] = {0, 7680, 15360};
  const int nc[3] = {7680, 7680, 6656};
  for (int c = 0; c < 3; ++c) {
    deq_kernel<1><<<dim3(nc[c] / 64, HIDC / 32), 256, 0, stream>>>(
        qw_gu, qz_gu, sc_gu, WT, cb[c], HIDC, 2752, 22016);
    qgemm_kernel<1, 64, HIDC><<<dim3(nc[c] / 256, NTOKC / 256), 512, 0, stream>>>(
        xh, WT, hbuf + cb[c] / 2, nullptr);
  }

  // GEMM2: deq all of W_dn (into dead xh+WT region), single GEMM
  deq_kernel<0><<<dim3(HIDC / 64, INTERC / 32), 256, 0, stream>>>(
      qw_dn, qz_dn, sc_dn, WTdn, 0, INTERC, 512, HIDC);
  qgemm_kernel<0, 172, INTERC><<<dim3(HIDC / 256, NTOKC / 256), 512, 0, stream>>>(
      hbuf, WTdn, nullptr, out);
}

// Round 11
// 1096.902 us; speedup vs baseline: 6.6902x; 1.0033x over previous
//
#include <hip/hip_runtime.h>
#include <hip/hip_bf16.h>
#include <hip/hip_fp16.h>
#include <cstdint>
#include <cstddef>

#define AS1 __attribute__((address_space(1)))
#define AS3 __attribute__((address_space(3)))

constexpr int HIDC   = 4096;
constexpr int INTERC = 11008;
constexpr int NTOKC  = 4096;          // B*S

using f32x4 = __attribute__((ext_vector_type(4))) float;
using f16x8 = __attribute__((ext_vector_type(8))) _Float16;

// ---------------- prologue kernels ----------------

// x f32 -> f16
__global__ void cvt_x_kernel(const float4* __restrict__ x, ushort4* __restrict__ xh, int n4) {
  int stride = gridDim.x * blockDim.x;
  for (int i = blockIdx.x * blockDim.x + threadIdx.x; i < n4; i += stride) {
    float4 v = x[i];
    ushort4 o;
    o.x = __builtin_bit_cast(unsigned short, __float2half(v.x));
    o.y = __builtin_bit_cast(unsigned short, __float2half(v.y));
    o.z = __builtin_bit_cast(unsigned short, __float2half(v.z));
    o.w = __builtin_bit_cast(unsigned short, __float2half(v.w));
    xh[i] = o;
  }
}

// Dequantize a column-chunk of W into WT[n'][K] f16 (row-major over output cols).
// GU=1: n' is the gate/up 16-col interleave of orig col n = mat*INTERC + hc:
//       n' = (hc>>4)*32 + mat*16 + (hc&15)
// GU=0: n' = n.  Block = 64 n' x 32 k tile; 256 threads = 32 k x 8 word-slots.
template <int GU>
__global__ void deq_kernel(const uint32_t* __restrict__ qw, const uint32_t* __restrict__ qz,
                           const float* __restrict__ sc, __half* __restrict__ WT,
                           int cbase, int K, int Wn8, int Nsc) {
  __shared__ __align__(16) __half tile[64][32];
  const int tid = threadIdx.x;
  const int bx = blockIdx.x;
  const int k0 = blockIdx.y * 32;
  const int k  = tid & 31, ws = tid >> 5;
  const int g  = (k0 + k) >> 7;
  int wordidx, nbase, nploc0;
  if (GU) {
    const int n0p = cbase + bx * 64;   // n' base (64-aligned)
    const int h0  = n0p >> 1;          // hc base
    const int mat = ws >> 2, wsq = ws & 3;
    wordidx = (mat * INTERC + h0) / 8 + wsq;
    nbase   = mat * INTERC + h0 + wsq * 8;
    nploc0  = ((wsq >> 1) << 5) + mat * 16 + ((wsq & 1) << 3);
  } else {
    const int n0 = cbase + bx * 64;
    wordidx = n0 / 8 + ws;
    nbase   = n0 + ws * 8;
    nploc0  = ws * 8;
  }
  uint32_t q  = qw[(size_t)(k0 + k) * Wn8 + wordidx];
  uint32_t zw = qz[(size_t)g * Wn8 + wordidx];
#pragma unroll
  for (int j = 0; j < 8; ++j) {
    float v = (float)((q >> (4 * j)) & 0xFu);
    float z = (float)((zw >> (4 * j)) & 0xFu);
    float s = sc[(size_t)g * Nsc + nbase + j];
    tile[nploc0 + j][k] = __float2half((v - z) * s);
  }
  __syncthreads();
  const int nl = tid >> 2, kc = (tid & 3) * 8;
  uint4 vv = *(const uint4*)&tile[nl][kc];
  *(uint4*)&WT[(size_t)(bx * 64 + nl) * K + k0 + kc] = vv;
}

// -------- pure-f16 GEMM, 256x256, counted-vmcnt depth-1.5 pipeline --------
// 512 threads = 8 waves (2M x 4N), per-wave 128x64 out, BK=64, 16x16x32 f16 MFMA.
// LDS 128KB: 2 bufs x (A[256][64] 32KB + B[256][64] 32KB), XOR swizzle
// byte ^= (row&7)<<4 via pre-swizzled gload SOURCE (LDS dest linear).
// Grid: 1D, bijective XCD chunking (grid%8==0), mt FASTEST within a chunk so
// consecutive blocks (same XCD) share one B-panel (stays in that XCD's L2);
// A streams through shared L3.
// Waits: end-ph2 vmcnt(4) (retires THIS tile's A-h1), end-ph4 vmcnt(2)
// (retires next tile's B + A-h0; A-h1 stays in flight). Never vmcnt(0) mid-loop.
template <int DUAL, int NT, int K>
__global__ __launch_bounds__(512, 1) void qgemm_kernel(
    const __half* __restrict__ A, const __half* __restrict__ B,
    __half* __restrict__ Hout, float* __restrict__ Fout) {
  __shared__ __align__(16) char lds[131072];
  const int tid  = threadIdx.x;
  const int lane = tid & 63;
  const int w    = tid >> 6;
  const int wr   = w >> 2, wc = w & 3;
  const int fr   = lane & 15, fq = lane >> 4;

  const int nwg8 = (int)gridDim.x >> 3;
  const int g2   = ((int)blockIdx.x & 7) * nwg8 + ((int)blockIdx.x >> 3);
  const int nt   = g2 >> 4;            // NTOKC/256 = 16 M-tiles, mt fastest
  const int mt   = g2 & 15;
  const int row0 = mt * 256, col0 = nt * 256;

  int a_src[4], b_src[4];
#pragma unroll
  for (int i = 0; i < 4; ++i) {
    int o = i * 8192 + tid * 16;
    int r = o >> 7;
    int b = (o & 127) ^ ((r & 7) << 4);
    a_src[i] = (row0 + r) * K + (b >> 1);
    b_src[i] = (col0 + r) * K + (b >> 1);
  }

  f32x4 acc[8][4] = {};
  f16x8 av[4], bv0[4], bv1[4];

  auto glA = [&](int i, int kt, int buf) {
    __builtin_amdgcn_global_load_lds(
        (const AS1 uint32_t*)(A + (size_t)a_src[i] + (size_t)kt * 64),
        (AS3 uint32_t*)(lds + buf * 65536 + i * 8192 + w * 1024), 16, 0, 0);
  };
  auto glB = [&](int i, int kt, int buf) {
    __builtin_amdgcn_global_load_lds(
        (const AS1 uint32_t*)(B + (size_t)b_src[i] + (size_t)kt * 64),
        (AS3 uint32_t*)(lds + buf * 65536 + 32768 + i * 8192 + w * 1024), 16, 0, 0);
  };
  auto rdA = [&](int buf, int mh, int kk) {
    const int bb = (((kk << 2) | fq) ^ (fr & 7)) << 4;
    const char* base = lds + buf * 65536;
#pragma unroll
    for (int j = 0; j < 4; ++j)
      av[j] = *(const f16x8*)(base + (wr * 128 + mh * 64 + j * 16 + fr) * 128 + bb);
  };
  auto rdB = [&](int buf, int kk, f16x8* dst) {
    const int bb = (((kk << 2) | fq) ^ (fr & 7)) << 4;
    const char* base = lds + buf * 65536 + 32768;
#pragma unroll
    for (int n = 0; n < 4; ++n)
      dst[n] = *(const f16x8*)(base + (wc * 64 + n * 16 + fr) * 128 + bb);
  };
  auto mfma16 = [&](f16x8* bvp, int mh) {
    __builtin_amdgcn_s_setprio(1);
#pragma unroll
    for (int j = 0; j < 4; ++j)
#pragma unroll
      for (int n = 0; n < 4; ++n)
        acc[mh * 4 + j][n] =
            __builtin_amdgcn_mfma_f32_16x16x32_f16(av[j], bvp[n], acc[mh * 4 + j][n], 0, 0, 0);
    __builtin_amdgcn_s_setprio(0);
  };

  // prologue: tile 0, issue order B0..B3, A0, A2, A1, A3; leave A-h1 in flight
  glB(0, 0, 0); glB(1, 0, 0); glB(2, 0, 0); glB(3, 0, 0);
  glA(0, 0, 0); glA(2, 0, 0); glA(1, 0, 0); glA(3, 0, 0);
  asm volatile("s_waitcnt vmcnt(2)" ::: "memory");
  asm volatile("s_barrier" ::: "memory");

#pragma unroll 1
  for (int kt = 0; kt < NT; ++kt) {
    const int cur = kt & 1, nxt = cur ^ 1;
    const bool stg = (kt + 1 < NT);
    // ph1: (mh0, kk0)
    if (stg) { glB(0, kt + 1, nxt); glB(1, kt + 1, nxt); }
    rdB(cur, 0, bv0);
    rdA(cur, 0, 0);
    mfma16(bv0, 0);
    // ph2: (mh0, kk1)
    if (stg) { glB(2, kt + 1, nxt); glB(3, kt + 1, nxt); }
    rdB(cur, 1, bv1);
    rdA(cur, 0, 1);
    mfma16(bv1, 0);
    if (stg) asm volatile("s_waitcnt vmcnt(4)" ::: "memory");
    else     asm volatile("s_waitcnt vmcnt(0)" ::: "memory");
    asm volatile("s_barrier" ::: "memory");
    // ph3: (mh1, kk0)
    if (stg) { glA(0, kt + 1, nxt); glA(2, kt + 1, nxt); }
    rdA(cur, 1, 0);
    mfma16(bv0, 1);
    // ph4: (mh1, kk1)
    if (stg) { glA(1, kt + 1, nxt); glA(3, kt + 1, nxt); }
    rdA(cur, 1, 1);
    mfma16(bv1, 1);
    if (stg) asm volatile("s_waitcnt vmcnt(2)" ::: "memory");
    asm volatile("s_barrier" ::: "memory");
  }

  // ---- epilogue — C/D map: col = lane&15, row = (lane>>4)*4 + reg ----
  if (DUAL) {
#pragma unroll
    for (int mi = 0; mi < 8; ++mi) {
      const int rr = row0 + wr * 128 + mi * 16 + fq * 4;
#pragma unroll
      for (int pp = 0; pp < 2; ++pp) {
        const int hcol = nt * 128 + (wc * 2 + pp) * 16 + fr;
#pragma unroll
        for (int r = 0; r < 4; ++r) {
          float gv = acc[mi][2 * pp][r];
          float uv = acc[mi][2 * pp + 1][r];
          float hv = gv / (1.0f + __expf(-gv)) * uv;   // silu(g)*u
          Hout[(size_t)(rr + r) * INTERC + hcol] = __float2half(hv);
        }
      }
    }
  } else {
#pragma unroll
    for (int mi = 0; mi < 8; ++mi) {
      const int rr = row0 + wr * 128 + mi * 16 + fq * 4;
#pragma unroll
      for (int ni = 0; ni < 4; ++ni) {
        const int cc = nt * 256 + wc * 64 + ni * 16 + fr;
#pragma unroll
        for (int r = 0; r < 4; ++r)
          Fout[(size_t)(rr + r) * HIDC + cc] = acc[mi][ni][r];
      }
    }
  }
}

// ---------------- launch ----------------
extern "C" void kernel_launch(void* const* d_in, const int* in_sizes, int n_in,
                              void* d_out, int out_size, void* d_ws, size_t ws_size,
                              hipStream_t stream) {
  const float*    x     = (const float*)d_in[0];
  const uint32_t* qw_gu = (const uint32_t*)d_in[1];
  const uint32_t* qz_gu = (const uint32_t*)d_in[2];
  const float*    sc_gu = (const float*)d_in[3];
  const uint32_t* qw_dn = (const uint32_t*)d_in[4];
  const uint32_t* qz_dn = (const uint32_t*)d_in[5];
  const float*    sc_dn = (const float*)d_in[6];
  float* out = (float*)d_out;

  // workspace (190.9 MB peak):
  //   [0, 33.5MB)        xh (f16 x)       — dead after GEMM1
  //   [33.5, 100.7MB)    WT gu chunk (<=67.1MB)
  //   [100.7, 190.9MB)   hbuf (f16 h)
  //   WTdn (90.2MB) reuses [0, 90.2MB) after GEMM1 (stream-ordered)
  char* ws = (char*)d_ws;
  __half* xh   = (__half*)(ws);
  __half* WT   = (__half*)(ws + 33554432);
  __half* hbuf = (__half*)(ws + 100663296);
  __half* WTdn = (__half*)(ws);

  cvt_x_kernel<<<2048, 256, 0, stream>>>((const float4*)x, (ushort4*)xh, NTOKC * HIDC / 4);

  // GEMM1 in 3 col' chunks (8192, 8192, 5632 of 22016): deq -> GEMM -> next
  const int cb[3] = {0, 8192, 16384};
  const int nc[3] = {8192, 8192, 5632};
  for (int c = 0; c < 3; ++c) {
    deq_kernel<1><<<dim3(nc[c] / 64, HIDC / 32), 256, 0, stream>>>(
        qw_gu, qz_gu, sc_gu, WT, cb[c], HIDC, 2752, 22016);
    qgemm_kernel<1, 64, HIDC><<<(nc[c] / 256) * 16, 512, 0, stream>>>(
        xh, WT, hbuf + cb[c] / 2, nullptr);
  }

  // GEMM2: deq all of W_dn (into dead xh+WT region), single GEMM
  deq_kernel<0><<<dim3(HIDC / 64, INTERC / 32), 256, 0, stream>>>(
      qw_dn, qz_dn, sc_dn, WTdn, 0, INTERC, 512, HIDC);
  qgemm_kernel<0, 172, INTERC><<<(HIDC / 256) * 16, 512, 0, stream>>>(
      hbuf, WTdn, nullptr, out);
}